// Round 1
// baseline (337.472 us; speedup 1.0000x reference)
//
#include <hip/hip_runtime.h>

#define V_CNT 6890
#define N_B 512
#define NJ 24
#define NP 207   // (24-1)*9
#define TN 32    // n-tile in main kernel

typedef float f4u __attribute__((ext_vector_type(4), aligned(4)));   // unaligned-capable
typedef float f4a __attribute__((ext_vector_type(4)));               // 16B aligned

__device__ __constant__ int PAR[24] = {0,0,0,0,1,2,3,4,5,6,7,8,9,9,9,12,13,14,16,17,18,19,20,21};

// ---------------- Kernel 1: JS[24][3][10], JT[24][3] ----------------
__global__ __launch_bounds__(256) void k_jsjt(const float* __restrict__ jreg,
                                              const float* __restrict__ sdirs,
                                              const float* __restrict__ vtemp,
                                              float* __restrict__ ws_js) {
    int j = blockIdx.x;
    int tid = threadIdx.x;
    float acc[33];
#pragma unroll
    for (int i = 0; i < 33; i++) acc[i] = 0.f;
    for (int v = tid; v < V_CNT; v += 256) {
        float r = jreg[j * V_CNT + v];
        const float* sd = sdirs + v * 30;
#pragma unroll
        for (int i = 0; i < 30; i++) acc[i] += r * sd[i];
        acc[30] += r * vtemp[v * 3 + 0];
        acc[31] += r * vtemp[v * 3 + 1];
        acc[32] += r * vtemp[v * 3 + 2];
    }
    __shared__ float red[33][257];
#pragma unroll
    for (int i = 0; i < 33; i++) red[i][tid] = acc[i];
    __syncthreads();
    if (tid < 33) {
        float s = 0.f;
        for (int t = 0; t < 256; t++) s += red[tid][t];
        if (tid < 30) ws_js[j * 30 + tid] = s;          // JS
        else          ws_js[720 + j * 3 + (tid - 30)] = s; // JT
    }
}

// ---------------- Kernel 2: per-n chain -> G'[n][24][12], lrotmin[n][207] ----------------
__global__ __launch_bounds__(64) void k_chain(const float* __restrict__ beta,
                                              const float* __restrict__ pose,
                                              const float* __restrict__ ws_js,
                                              float* __restrict__ ws_g,
                                              float* __restrict__ ws_lr) {
    int n = blockIdx.x;
    int t = threadIdx.x;
    __shared__ float Rl[24][9];
    __shared__ float Jl[24][3];
    __shared__ float Tm[24][16];
    __shared__ float G[24][16];

    if (t < 24) {
        float x = pose[n * 72 + t * 3 + 0];
        float y = pose[n * 72 + t * 3 + 1];
        float z = pose[n * 72 + t * 3 + 2];
        float th = sqrtf(x * x + y * y + z * z) + 1e-8f;
        float inv = 1.f / th;
        float rx = x * inv, ry = y * inv, rz = z * inv;
        float c = cosf(th), s = sinf(th), omc = 1.f - c;
        Rl[t][0] = c + omc * rx * rx;
        Rl[t][1] = omc * rx * ry - s * rz;
        Rl[t][2] = omc * rx * rz + s * ry;
        Rl[t][3] = omc * ry * rx + s * rz;
        Rl[t][4] = c + omc * ry * ry;
        Rl[t][5] = omc * ry * rz - s * rx;
        Rl[t][6] = omc * rz * rx - s * ry;
        Rl[t][7] = omc * rz * ry + s * rx;
        Rl[t][8] = c + omc * rz * rz;
        const float* JS = ws_js;
        const float* JT = ws_js + 720;
#pragma unroll
        for (int cc = 0; cc < 3; cc++) {
            float a = JT[t * 3 + cc];
#pragma unroll
            for (int b = 0; b < 10; b++) a += beta[n * 10 + b] * JS[(t * 3 + cc) * 10 + b];
            Jl[t][cc] = a;
        }
    }
    __syncthreads();
    if (t < 24) {
        int p = PAR[t];
        float tx, ty, tz;
        if (t == 0) { tx = Jl[0][0]; ty = Jl[0][1]; tz = Jl[0][2]; }
        else { tx = Jl[t][0] - Jl[p][0]; ty = Jl[t][1] - Jl[p][1]; tz = Jl[t][2] - Jl[p][2]; }
        Tm[t][0] = Rl[t][0]; Tm[t][1] = Rl[t][1]; Tm[t][2]  = Rl[t][2]; Tm[t][3]  = tx;
        Tm[t][4] = Rl[t][3]; Tm[t][5] = Rl[t][4]; Tm[t][6]  = Rl[t][5]; Tm[t][7]  = ty;
        Tm[t][8] = Rl[t][6]; Tm[t][9] = Rl[t][7]; Tm[t][10] = Rl[t][8]; Tm[t][11] = tz;
        Tm[t][12] = 0.f; Tm[t][13] = 0.f; Tm[t][14] = 0.f; Tm[t][15] = 1.f;
    }
    __syncthreads();
    if (t < 16) G[0][t] = Tm[0][t];
    __syncthreads();
    for (int i = 1; i < 24; i++) {
        int p = PAR[i];
        if (t < 16) {
            int a = t >> 2, b = t & 3;
            float s = G[p][a * 4 + 0] * Tm[i][0 * 4 + b]
                    + G[p][a * 4 + 1] * Tm[i][1 * 4 + b]
                    + G[p][a * 4 + 2] * Tm[i][2 * 4 + b]
                    + G[p][a * 4 + 3] * Tm[i][3 * 4 + b];
            G[i][t] = s;
        }
        __syncthreads();
    }
    if (t < 24) {
        float jx = Jl[t][0], jy = Jl[t][1], jz = Jl[t][2];
        float* outp = ws_g + (n * 24 + t) * 12;
#pragma unroll
        for (int a = 0; a < 3; a++) {
            float g0 = G[t][a * 4 + 0], g1 = G[t][a * 4 + 1];
            float g2 = G[t][a * 4 + 2], g3 = G[t][a * 4 + 3];
            outp[a * 4 + 0] = g0;
            outp[a * 4 + 1] = g1;
            outp[a * 4 + 2] = g2;
            outp[a * 4 + 3] = g3 - (g0 * jx + g1 * jy + g2 * jz);
        }
    }
    for (int idx = t; idx < NP; idx += 64) {
        int j = 1 + idx / 9;
        int e = idx - (j - 1) * 9;
        float d = (e == 0 || e == 4 || e == 8) ? 1.f : 0.f;
        ws_lr[n * NP + idx] = Rl[j][e] - d;
    }
}

// ---------------- Kernel 3: fused shape-blend + pose-blend GEMM + LBS ----------------
// grid: (27 v-tiles, 16 n-tiles), 256 threads. thread = 1 vertex x 32 n.
__global__ __launch_bounds__(256) void k_main(const float* __restrict__ beta,
                                              const float* __restrict__ vtemp,
                                              const float* __restrict__ sdirs,
                                              const float* __restrict__ pdirs,
                                              const float* __restrict__ wts,
                                              const float* __restrict__ ws_g,
                                              const float* __restrict__ ws_lr,
                                              float* __restrict__ out) {
    int tid = threadIdx.x;
    int v = blockIdx.x * 256 + tid;
    int n0 = blockIdx.y * TN;
    int ve = v < V_CNT ? v : V_CNT - 1;

    // lrotmin tile transposed: lr_t[k][n], row stride 36 (16B aligned rows)
    __shared__ float lr_t[NP * 36];
#pragma unroll 1
    for (int ni = 0; ni < TN; ni++) {
        if (tid < NP) lr_t[tid * 36 + ni] = ws_lr[(n0 + ni) * NP + tid];
    }
    __syncthreads();

    float acc[TN][3];
    // shape blend: acc = v_template + beta @ shapedirs  (beta reads are uniform -> s_load)
    {
        float sd[30];
        const float* sp = sdirs + ve * 30;
#pragma unroll
        for (int i = 0; i < 30; i++) sd[i] = sp[i];
        float vt0 = vtemp[ve * 3 + 0], vt1 = vtemp[ve * 3 + 1], vt2 = vtemp[ve * 3 + 2];
#pragma unroll
        for (int ni = 0; ni < TN; ni++) {
            float a0 = vt0, a1 = vt1, a2 = vt2;
#pragma unroll
            for (int b = 0; b < 10; b++) {
                float be = beta[(n0 + ni) * 10 + b];
                a0 += be * sd[b];
                a1 += be * sd[10 + b];
                a2 += be * sd[20 + b];
            }
            acc[ni][0] = a0; acc[ni][1] = a1; acc[ni][2] = a2;
        }
    }

    // pose-blend GEMM over k=0..206
    const float* p0 = pdirs + (ve * 3 + 0) * NP;
    const float* p1 = pdirs + (ve * 3 + 1) * NP;
    const float* p2 = pdirs + (ve * 3 + 2) * NP;
#pragma unroll 1
    for (int k0 = 0; k0 < 204; k0 += 4) {
        f4u a0 = *(const f4u*)(p0 + k0);
        f4u a1 = *(const f4u*)(p1 + k0);
        f4u a2 = *(const f4u*)(p2 + k0);
#pragma unroll
        for (int kk = 0; kk < 4; kk++) {
            float q0 = a0[kk], q1 = a1[kk], q2 = a2[kk];
#pragma unroll
            for (int g = 0; g < 8; g++) {
                f4a l = *(const f4a*)&lr_t[(k0 + kk) * 36 + g * 4];
#pragma unroll
                for (int u = 0; u < 4; u++) {
                    float lv = l[u];
                    acc[g * 4 + u][0] += lv * q0;
                    acc[g * 4 + u][1] += lv * q1;
                    acc[g * 4 + u][2] += lv * q2;
                }
            }
        }
    }
#pragma unroll
    for (int kk = 0; kk < 3; kk++) {
        int k = 204 + kk;
        float q0 = p0[k], q1 = p1[k], q2 = p2[k];
#pragma unroll
        for (int g = 0; g < 8; g++) {
            f4a l = *(const f4a*)&lr_t[k * 36 + g * 4];
#pragma unroll
            for (int u = 0; u < 4; u++) {
                float lv = l[u];
                acc[g * 4 + u][0] += lv * q0;
                acc[g * 4 + u][1] += lv * q1;
                acc[g * 4 + u][2] += lv * q2;
            }
        }
    }

    // stage this block's weight rows into LDS (reuse lr_t space), row stride 25 (odd -> no bank conflicts)
    __syncthreads();
    {
        const f4a* wrow = (const f4a*)(wts + ve * 24);
#pragma unroll
        for (int q = 0; q < 6; q++) {
            f4a wv = wrow[q];
#pragma unroll
            for (int u = 0; u < 4; u++) lr_t[tid * 25 + q * 4 + u] = wv[u];
        }
    }
    __syncthreads();

    // LBS: G' reads are wave-uniform -> scalar loads on the s-pipe
#pragma unroll
    for (int ni = 0; ni < TN; ni++) {
        float px = acc[ni][0], py = acc[ni][1], pz = acc[ni][2];
        const float* gp = ws_g + (n0 + ni) * (24 * 12);
        float o0 = 0.f, o1 = 0.f, o2 = 0.f;
#pragma unroll 4
        for (int j = 0; j < 24; j++) {
            float wj = lr_t[tid * 25 + j];
            const float* g = gp + j * 12;
            float r0 = g[3]  + g[0] * px + g[1] * py + g[2]  * pz;
            float r1 = g[7]  + g[4] * px + g[5] * py + g[6]  * pz;
            float r2 = g[11] + g[8] * px + g[9] * py + g[10] * pz;
            o0 += wj * r0; o1 += wj * r1; o2 += wj * r2;
        }
        if (v < V_CNT) {
            float* op = out + ((n0 + ni) * V_CNT + v) * 3;
            op[0] = o0; op[1] = o1; op[2] = o2;
        }
    }
}

extern "C" void kernel_launch(void* const* d_in, const int* in_sizes, int n_in,
                              void* d_out, int out_size, void* d_ws, size_t ws_size,
                              hipStream_t stream) {
    const float* beta  = (const float*)d_in[0];
    const float* pose  = (const float*)d_in[1];
    const float* vtemp = (const float*)d_in[2];
    const float* sdirs = (const float*)d_in[3];
    const float* pdirs = (const float*)d_in[4];
    const float* jreg  = (const float*)d_in[5];
    const float* wts   = (const float*)d_in[6];
    float* ws = (float*)d_ws;
    float* ws_js = ws;                     // 792 floats (pad to 800)
    float* ws_g  = ws + 800;               // 512*24*12 = 147456 floats
    float* ws_lr = ws + 800 + 147456;      // 512*207  = 105984 floats
    float* out = (float*)d_out;

    k_jsjt<<<dim3(24), dim3(256), 0, stream>>>(jreg, sdirs, vtemp, ws_js);
    k_chain<<<dim3(N_B), dim3(64), 0, stream>>>(beta, pose, ws_js, ws_g, ws_lr);
    k_main<<<dim3(27, 16), dim3(256), 0, stream>>>(beta, vtemp, sdirs, pdirs, wts, ws_g, ws_lr, out);
}

// Round 2
// 161.320 us; speedup vs baseline: 2.0919x; 2.0919x over previous
//
#include <hip/hip_runtime.h>

#define V_CNT 6890
#define N_B 512
#define NJ 24
#define NP 207          // (24-1)*9
#define KPAD 224        // 207 lrotmin + 10 beta + 7 zero
#define RTOT 20670      // V*3
#define RPAD 20736      // multiple of 128

typedef __attribute__((ext_vector_type(4))) float f32x4;
typedef __attribute__((ext_vector_type(8))) short s16x8;
typedef float f4a __attribute__((ext_vector_type(4)));

// ws layout (bytes); total ~31.9 MB
#define O_JS   0u         // 792 f32
#define O_PART 4096u      // 24*16*33 f32
#define O_G    65536u     // 512*288 f32
#define O_A    1048576u   // 512*224 bf16
#define O_B    1310720u   // 20736*224 bf16
#define O_PB   10616832u  // 512*20736 bf16

__device__ __constant__ int PAR[24] = {0,0,0,0,1,2,3,4,5,6,7,8,9,9,9,12,13,14,16,17,18,19,20,21};

__device__ __forceinline__ ushort f2bf(float f) {
    union { float f; unsigned u; } x; x.f = f;
    unsigned u = x.u + 0x7fffu + ((x.u >> 16) & 1u);
    return (ushort)(u >> 16);
}
__device__ __forceinline__ float bf2f(ushort h) {
    union { unsigned u; float f; } x; x.u = ((unsigned)h) << 16;
    return x.f;
}

// ---------- JS/JT stage 1: partial reductions, grid (16 chunks, 24 j) ----------
__global__ __launch_bounds__(256) void k_js1(const float* __restrict__ jreg,
                                             const float* __restrict__ sdirs,
                                             const float* __restrict__ vtemp,
                                             float* __restrict__ part) {
    int j = blockIdx.y, ch = blockIdx.x, tid = threadIdx.x;
    int v0 = ch * 432;
    int vend = v0 + 432; if (vend > V_CNT) vend = V_CNT;
    float acc[33];
#pragma unroll
    for (int i = 0; i < 33; i++) acc[i] = 0.f;
    for (int v = v0 + tid; v < vend; v += 256) {
        float r = jreg[j * V_CNT + v];
        const float* sd = sdirs + v * 30;
#pragma unroll
        for (int i = 0; i < 30; i++) acc[i] += r * sd[i];
        acc[30] += r * vtemp[v * 3 + 0];
        acc[31] += r * vtemp[v * 3 + 1];
        acc[32] += r * vtemp[v * 3 + 2];
    }
    __shared__ float red[33][257];
#pragma unroll
    for (int i = 0; i < 33; i++) red[i][tid] = acc[i];
    __syncthreads();
    for (int s = 128; s > 0; s >>= 1) {
        if (tid < s) {
#pragma unroll
            for (int i = 0; i < 33; i++) red[i][tid] += red[i][tid + s];
        }
        __syncthreads();
    }
    if (tid < 33) part[(j * 16 + ch) * 33 + tid] = red[tid][0];
}

// ---------- JS/JT stage 2: 1 block ----------
__global__ __launch_bounds__(256) void k_js2(const float* __restrict__ part,
                                             float* __restrict__ ws_js) {
    for (int t = threadIdx.x; t < 24 * 33; t += 256) {
        int j = t / 33, i = t - j * 33;
        float s = 0.f;
#pragma unroll
        for (int c = 0; c < 16; c++) s += part[(j * 16 + c) * 33 + i];
        if (i < 30) ws_js[j * 30 + i] = s;
        else        ws_js[720 + j * 3 + (i - 30)] = s;
    }
}

// ---------- build B matrix [RPAD][KPAD] bf16: posedirs|shapedirs|0 ----------
__global__ __launch_bounds__(256) void k_prep(const float* __restrict__ pdirs,
                                              const float* __restrict__ sdirs,
                                              ushort* __restrict__ Bm) {
    int t = blockIdx.x * 256 + threadIdx.x;         // 0 .. RPAD*KPAD
    if (t >= RPAD * KPAD) return;
    int r = t / KPAD;
    int k = t - r * KPAD;
    float v = 0.f;
    if (r < RTOT) {
        if (k < NP)        v = pdirs[r * NP + k];
        else if (k < 217)  v = sdirs[r * 10 + (k - NP)];
    }
    Bm[t] = f2bf(v);
}

// ---------- per-n chain -> G'[n][24][12] f32, A[n][224] bf16 ----------
__global__ __launch_bounds__(64) void k_chain(const float* __restrict__ beta,
                                              const float* __restrict__ pose,
                                              const float* __restrict__ ws_js,
                                              float* __restrict__ ws_g,
                                              ushort* __restrict__ Am) {
    int n = blockIdx.x;
    int t = threadIdx.x;
    __shared__ float Rl[24][9];
    __shared__ float Jl[24][3];
    __shared__ float Tm[24][16];
    __shared__ float G[24][16];

    if (t < 24) {
        float x = pose[n * 72 + t * 3 + 0];
        float y = pose[n * 72 + t * 3 + 1];
        float z = pose[n * 72 + t * 3 + 2];
        float th = sqrtf(x * x + y * y + z * z) + 1e-8f;
        float inv = 1.f / th;
        float rx = x * inv, ry = y * inv, rz = z * inv;
        float c = cosf(th), s = sinf(th), omc = 1.f - c;
        Rl[t][0] = c + omc * rx * rx;
        Rl[t][1] = omc * rx * ry - s * rz;
        Rl[t][2] = omc * rx * rz + s * ry;
        Rl[t][3] = omc * ry * rx + s * rz;
        Rl[t][4] = c + omc * ry * ry;
        Rl[t][5] = omc * ry * rz - s * rx;
        Rl[t][6] = omc * rz * rx - s * ry;
        Rl[t][7] = omc * rz * ry + s * rx;
        Rl[t][8] = c + omc * rz * rz;
        const float* JS = ws_js;
        const float* JT = ws_js + 720;
#pragma unroll
        for (int cc = 0; cc < 3; cc++) {
            float a = JT[t * 3 + cc];
#pragma unroll
            for (int b = 0; b < 10; b++) a += beta[n * 10 + b] * JS[(t * 3 + cc) * 10 + b];
            Jl[t][cc] = a;
        }
    }
    __syncthreads();
    if (t < 24) {
        int p = PAR[t];
        float tx, ty, tz;
        if (t == 0) { tx = Jl[0][0]; ty = Jl[0][1]; tz = Jl[0][2]; }
        else { tx = Jl[t][0] - Jl[p][0]; ty = Jl[t][1] - Jl[p][1]; tz = Jl[t][2] - Jl[p][2]; }
        Tm[t][0] = Rl[t][0]; Tm[t][1] = Rl[t][1]; Tm[t][2]  = Rl[t][2]; Tm[t][3]  = tx;
        Tm[t][4] = Rl[t][3]; Tm[t][5] = Rl[t][4]; Tm[t][6]  = Rl[t][5]; Tm[t][7]  = ty;
        Tm[t][8] = Rl[t][6]; Tm[t][9] = Rl[t][7]; Tm[t][10] = Rl[t][8]; Tm[t][11] = tz;
        Tm[t][12] = 0.f; Tm[t][13] = 0.f; Tm[t][14] = 0.f; Tm[t][15] = 1.f;
    }
    __syncthreads();
    if (t < 16) G[0][t] = Tm[0][t];
    __syncthreads();
    for (int i = 1; i < 24; i++) {
        int p = PAR[i];
        if (t < 16) {
            int a = t >> 2, b = t & 3;
            float s = G[p][a * 4 + 0] * Tm[i][0 * 4 + b]
                    + G[p][a * 4 + 1] * Tm[i][1 * 4 + b]
                    + G[p][a * 4 + 2] * Tm[i][2 * 4 + b]
                    + G[p][a * 4 + 3] * Tm[i][3 * 4 + b];
            G[i][t] = s;
        }
        __syncthreads();
    }
    if (t < 24) {
        float jx = Jl[t][0], jy = Jl[t][1], jz = Jl[t][2];
        float* outp = ws_g + (n * 24 + t) * 12;
#pragma unroll
        for (int a = 0; a < 3; a++) {
            float g0 = G[t][a * 4 + 0], g1 = G[t][a * 4 + 1];
            float g2 = G[t][a * 4 + 2], g3 = G[t][a * 4 + 3];
            outp[a * 4 + 0] = g0;
            outp[a * 4 + 1] = g1;
            outp[a * 4 + 2] = g2;
            outp[a * 4 + 3] = g3 - (g0 * jx + g1 * jy + g2 * jz);
        }
    }
    // A row for GEMM: [lrotmin(207) | beta(10) | 0(7)] as bf16
    for (int idx = t; idx < KPAD; idx += 64) {
        float val;
        if (idx < NP) {
            int j = 1 + idx / 9;
            int e = idx - (j - 1) * 9;
            float d = (e == 0 || e == 4 || e == 8) ? 1.f : 0.f;
            val = Rl[j][e] - d;
        } else if (idx < 217) {
            val = beta[n * 10 + (idx - NP)];
        } else val = 0.f;
        Am[n * KPAD + idx] = f2bf(val);
    }
}

// ---------- MFMA GEMM: C[512][RPAD] = A[512][224] x B[224][RPAD] (B stored row=r) ----------
// block tile 64(n) x 128(r); 4 waves, wave tile 32x64; 16x16x32 bf16 MFMA
__global__ __launch_bounds__(256) void k_gemm(const ushort* __restrict__ A,
                                              const ushort* __restrict__ B,
                                              ushort* __restrict__ C) {
    __shared__ __align__(16) ushort a_lds[64 * 40];   // pad 32->40 (2-way max = free)
    __shared__ __align__(16) ushort b_lds[128 * 40];
    int tid = threadIdx.x;
    int rblk = blockIdx.x * 128;
    int n0 = blockIdx.y * 64;
    int w = tid >> 6, lane = tid & 63;
    int quad = lane >> 4, lm = lane & 15;
    int m0w = (w >> 1) * 32, r0w = (w & 1) * 64;

    f32x4 acc[2][4];
#pragma unroll
    for (int a = 0; a < 2; a++)
#pragma unroll
        for (int b = 0; b < 4; b++) acc[a][b] = (f32x4)0.f;

    int srow = tid >> 2, koff = (tid & 3) * 8;
    const ushort* ag  = A + (n0 + srow) * KPAD + koff;
    const ushort* bg1 = B + (rblk + srow) * KPAD + koff;
    const ushort* bg2 = B + (rblk + srow + 64) * KPAD + koff;

#pragma unroll 1
    for (int kc = 0; kc < 7; kc++) {
        s16x8 av  = *(const s16x8*)(ag  + kc * 32);
        s16x8 bv1 = *(const s16x8*)(bg1 + kc * 32);
        s16x8 bv2 = *(const s16x8*)(bg2 + kc * 32);
        __syncthreads();
        *(s16x8*)&a_lds[srow * 40 + koff] = av;
        *(s16x8*)&b_lds[srow * 40 + koff] = bv1;
        *(s16x8*)&b_lds[(srow + 64) * 40 + koff] = bv2;
        __syncthreads();
        s16x8 af[2], bf[4];
#pragma unroll
        for (int mt = 0; mt < 2; mt++)
            af[mt] = *(const s16x8*)&a_lds[(m0w + mt * 16 + lm) * 40 + quad * 8];
#pragma unroll
        for (int rt = 0; rt < 4; rt++)
            bf[rt] = *(const s16x8*)&b_lds[(r0w + rt * 16 + lm) * 40 + quad * 8];
#pragma unroll
        for (int mt = 0; mt < 2; mt++)
#pragma unroll
            for (int rt = 0; rt < 4; rt++)
                acc[mt][rt] = __builtin_amdgcn_mfma_f32_16x16x32_bf16(af[mt], bf[rt], acc[mt][rt], 0, 0, 0);
    }
    // epilogue: D row = quad*4+i (n), col = lm (r); store bf16, pad cols are in-bounds scratch
#pragma unroll
    for (int mt = 0; mt < 2; mt++) {
#pragma unroll
        for (int rt = 0; rt < 4; rt++) {
            int col = rblk + r0w + rt * 16 + lm;
#pragma unroll
            for (int i = 0; i < 4; i++) {
                int row = n0 + m0w + mt * 16 + quad * 4 + i;
                C[row * RPAD + col] = f2bf(acc[mt][rt][i]);
            }
        }
    }
}

// ---------- LBS: block = (one n, 256 v); G'[n] via scalar pipe ----------
__global__ __launch_bounds__(256) void k_lbs(const ushort* __restrict__ pb,
                                             const float* __restrict__ vtemp,
                                             const float* __restrict__ wts,
                                             const float* __restrict__ ws_g,
                                             float* __restrict__ out) {
    int v = blockIdx.x * 256 + threadIdx.x;
    int n = blockIdx.y;
    if (v >= V_CNT) return;
    const ushort* pp = pb + n * RPAD + v * 3;
    float px = bf2f(pp[0]) + vtemp[v * 3 + 0];
    float py = bf2f(pp[1]) + vtemp[v * 3 + 1];
    float pz = bf2f(pp[2]) + vtemp[v * 3 + 2];
    float w[24];
    {
        const f4a* wr = (const f4a*)(wts + v * 24);
#pragma unroll
        for (int q = 0; q < 6; q++) {
            f4a t = wr[q];
#pragma unroll
            for (int u = 0; u < 4; u++) w[q * 4 + u] = t[u];
        }
    }
    float T[12];
#pragma unroll
    for (int q = 0; q < 12; q++) T[q] = 0.f;
    const float* g = ws_g + n * 288;   // block-uniform -> s_load
#pragma unroll
    for (int j = 0; j < 24; j++) {
        float wj = w[j];
#pragma unroll
        for (int q = 0; q < 12; q++) T[q] += wj * g[j * 12 + q];
    }
    float o0 = T[3]  + T[0] * px + T[1] * py + T[2]  * pz;
    float o1 = T[7]  + T[4] * px + T[5] * py + T[6]  * pz;
    float o2 = T[11] + T[8] * px + T[9] * py + T[10] * pz;
    float* op = out + (n * V_CNT + v) * 3;
    op[0] = o0; op[1] = o1; op[2] = o2;
}

extern "C" void kernel_launch(void* const* d_in, const int* in_sizes, int n_in,
                              void* d_out, int out_size, void* d_ws, size_t ws_size,
                              hipStream_t stream) {
    const float* beta  = (const float*)d_in[0];
    const float* pose  = (const float*)d_in[1];
    const float* vtemp = (const float*)d_in[2];
    const float* sdirs = (const float*)d_in[3];
    const float* pdirs = (const float*)d_in[4];
    const float* jreg  = (const float*)d_in[5];
    const float* wts   = (const float*)d_in[6];
    char* ws = (char*)d_ws;
    float*  ws_js   = (float*)(ws + O_JS);
    float*  ws_part = (float*)(ws + O_PART);
    float*  ws_g    = (float*)(ws + O_G);
    ushort* ws_A    = (ushort*)(ws + O_A);
    ushort* ws_B    = (ushort*)(ws + O_B);
    ushort* ws_pb   = (ushort*)(ws + O_PB);
    float* out = (float*)d_out;

    k_js1<<<dim3(16, 24), dim3(256), 0, stream>>>(jreg, sdirs, vtemp, ws_part);
    k_prep<<<dim3((RPAD * KPAD + 255) / 256), dim3(256), 0, stream>>>(pdirs, sdirs, ws_B);
    k_js2<<<dim3(1), dim3(256), 0, stream>>>(ws_part, ws_js);
    k_chain<<<dim3(N_B), dim3(64), 0, stream>>>(beta, pose, ws_js, ws_g, ws_A);
    k_gemm<<<dim3(RPAD / 128, N_B / 64), dim3(256), 0, stream>>>(ws_A, ws_B, ws_pb);
    k_lbs<<<dim3(27, N_B), dim3(256), 0, stream>>>(ws_pb, vtemp, wts, ws_g, out);
}